// Round 1
// baseline (16736.603 us; speedup 1.0000x reference)
//
#include <hip/hip_runtime.h>

#define BATCH 8192
#define SDIM  1024
#define HDIM  2048
#define DECD  1024
#define EMBD  256
#define G3    3072
#define VOCAB 169
#define TLEN  20
#define SOS_TOK 166
#define IGN_TOK 168
#define OUTC  166

// ---------------- generic fp32 GEMM: C = op(A[M,K] @ B[K,N] + bias) ----------------
#define BM  128
#define BN  128
#define BKK 16
#define LDS_A (BM + 4)
#define LDS_B (BN + 4)

__global__ __launch_bounds__(256, 2)
void gemm_f32(const float* __restrict__ A, const float* __restrict__ Bm,
              const float* __restrict__ bias, float* __restrict__ C,
              int M, int N, int K, int do_relu)
{
    __shared__ float As[BKK][LDS_A];
    __shared__ float Bs[BKK][LDS_B];
    const int tid = threadIdx.x;
    const int m0 = blockIdx.y * BM;
    const int n0 = blockIdx.x * BN;
    const int ty = tid >> 4;   // 0..15
    const int tx = tid & 15;   // 0..15

    float acc[8][8];
#pragma unroll
    for (int i = 0; i < 8; ++i)
#pragma unroll
        for (int j = 0; j < 8; ++j) acc[i][j] = 0.f;

    const int arow = tid >> 2;   // 0..63
    const int akq  = tid & 3;
    const int bkr  = tid >> 5;   // 0..7
    const int bnq  = tid & 31;

    for (int k0 = 0; k0 < K; k0 += BKK) {
#pragma unroll
        for (int h = 0; h < 2; ++h) {
            const int row = arow + h * 64;
            float4 av = *reinterpret_cast<const float4*>(&A[(size_t)(m0 + row) * K + k0 + akq * 4]);
            As[akq*4+0][row] = av.x;
            As[akq*4+1][row] = av.y;
            As[akq*4+2][row] = av.z;
            As[akq*4+3][row] = av.w;
        }
#pragma unroll
        for (int h = 0; h < 2; ++h) {
            const int kr = bkr + h * 8;
            float4 bv = *reinterpret_cast<const float4*>(&Bm[(size_t)(k0 + kr) * N + n0 + bnq * 4]);
            *reinterpret_cast<float4*>(&Bs[kr][bnq * 4]) = bv;
        }
        __syncthreads();
#pragma unroll
        for (int kk = 0; kk < BKK; ++kk) {
            float a[8], b[8];
            *reinterpret_cast<float4*>(&a[0]) = *reinterpret_cast<const float4*>(&As[kk][ty*8]);
            *reinterpret_cast<float4*>(&a[4]) = *reinterpret_cast<const float4*>(&As[kk][ty*8+4]);
            *reinterpret_cast<float4*>(&b[0]) = *reinterpret_cast<const float4*>(&Bs[kk][tx*8]);
            *reinterpret_cast<float4*>(&b[4]) = *reinterpret_cast<const float4*>(&Bs[kk][tx*8+4]);
#pragma unroll
            for (int i = 0; i < 8; ++i)
#pragma unroll
                for (int j = 0; j < 8; ++j)
                    acc[i][j] = fmaf(a[i], b[j], acc[i][j]);
        }
        __syncthreads();
    }

#pragma unroll
    for (int i = 0; i < 8; ++i) {
        const int gm = m0 + ty * 8 + i;
#pragma unroll
        for (int jj = 0; jj < 2; ++jj) {
            const int gn = n0 + tx * 8 + jj * 4;
            float4 o;
            float* op = &o.x;
#pragma unroll
            for (int j = 0; j < 4; ++j) {
                float v = acc[i][jj*4+j] + bias[gn + j];
                if (do_relu) v = fmaxf(v, 0.f);
                op[j] = v;
            }
            *reinterpret_cast<float4*>(&C[(size_t)gm * N + gn]) = o;
        }
    }
}

// ---------------- tokgi[v] = emb[v] @ Wih[0:256, :]  ([169, 3072]) ----------------
__global__ __launch_bounds__(256)
void tok_gi(const float* __restrict__ emb, const float* __restrict__ Wih,
            float* __restrict__ tg)
{
    __shared__ float es[EMBD];
    const int v = blockIdx.y;
    const int n = blockIdx.x * 256 + threadIdx.x;
    es[threadIdx.x] = emb[(size_t)v * EMBD + threadIdx.x];
    __syncthreads();
    float s = 0.f;
#pragma unroll 8
    for (int k = 0; k < EMBD; ++k)
        s = fmaf(es[k], Wih[(size_t)k * G3 + n], s);
    tg[(size_t)v * G3 + n] = s;
}

// ---------------- GRU gates (in-place h update) ----------------
__global__ __launch_bounds__(256)
void gru_gates(const float* __restrict__ gh, const float* __restrict__ gx0,
               const float* __restrict__ tokgi, const int* __restrict__ tseq,
               int t, float* __restrict__ hio)
{
    const int idx = blockIdx.x * 256 + threadIdx.x;   // b*1024 + j
    const int b = idx >> 10;
    const int j = idx & 1023;
    const int tok = (t == 0) ? SOS_TOK : tseq[(size_t)b * TLEN + (t - 1)];
    const size_t gb = (size_t)b * G3;
    const size_t tb = (size_t)tok * G3;
    const float ir  = tokgi[tb + j]        + gx0[gb + j];
    const float iz  = tokgi[tb + 1024 + j] + gx0[gb + 1024 + j];
    const float inn = tokgi[tb + 2048 + j] + gx0[gb + 2048 + j];
    const float hr = gh[gb + j];
    const float hz = gh[gb + 1024 + j];
    const float hn = gh[gb + 2048 + j];
    const float r = 1.f / (1.f + expf(-(ir + hr)));
    const float z = 1.f / (1.f + expf(-(iz + hz)));
    const float n = tanhf(inn + r * hn);
    const float hp = hio[idx];
    hio[idx] = (1.f - z) * n + z * hp;
}

// ---------------- fused logits + argmax + CE ----------------
// block = 256 threads = 4 waves; each wave owns 4 rows; 16 rows/block.
// vocab slots per lane: v = lane, lane+64, lane+128 (lane<41)
#define LROWS 16
#define LKC   256

__global__ __launch_bounds__(256, 2)
void logits_kernel(const float* __restrict__ h, const float* __restrict__ Wp,
                   const float* __restrict__ bp, const int* __restrict__ tseq,
                   int t, float* __restrict__ pred, float* __restrict__ accb)
{
    __shared__ float hs[LROWS][LKC];
    const int tid  = threadIdx.x;
    const int lane = tid & 63;
    const int wv   = tid >> 6;
    const int b0   = blockIdx.x * LROWS;
    const bool v2  = (lane < VOCAB - 128);   // lane < 41

    float acc0[4], acc1[4], acc2[4];
#pragma unroll
    for (int r = 0; r < 4; ++r) { acc0[r] = 0.f; acc1[r] = 0.f; acc2[r] = 0.f; }

    const int r0 = wv * 4;
    for (int kc = 0; kc < DECD; kc += LKC) {
        __syncthreads();
#pragma unroll
        for (int j = 0; j < 4; ++j) {
            const int f = tid + j * 256;      // float4 index
            const int row = f >> 6, c4 = f & 63;
            *reinterpret_cast<float4*>(&hs[row][c4*4]) =
                *reinterpret_cast<const float4*>(&h[(size_t)(b0+row)*DECD + kc + c4*4]);
        }
        __syncthreads();
        for (int k4 = 0; k4 < LKC/4; ++k4) {
            float4 hv[4];
#pragma unroll
            for (int r = 0; r < 4; ++r)
                hv[r] = *reinterpret_cast<const float4*>(&hs[r0+r][k4*4]);
#pragma unroll
            for (int kk = 0; kk < 4; ++kk) {
                const int kg = kc + k4*4 + kk;
                const float w0 = Wp[(size_t)kg*VOCAB + lane];
                const float w1 = Wp[(size_t)kg*VOCAB + lane + 64];
                const float w2 = v2 ? Wp[(size_t)kg*VOCAB + lane + 128] : 0.f;
#pragma unroll
                for (int r = 0; r < 4; ++r) {
                    const float hrk = (&hv[r].x)[kk];
                    acc0[r] = fmaf(hrk, w0, acc0[r]);
                    acc1[r] = fmaf(hrk, w1, acc1[r]);
                    acc2[r] = fmaf(hrk, w2, acc2[r]);
                }
            }
        }
    }

    float wnll = 0.f, wcnt = 0.f;
    for (int r = 0; r < 4; ++r) {
        const int b = b0 + r0 + r;
        const float l0 = acc0[r] + bp[lane];
        const float l1 = acc1[r] + bp[lane + 64];
        const float l2 = v2 ? (acc2[r] + bp[lane + 128]) : 0.f;
        // local (max, min-index)
        float m = l0; int mi = lane;
        if (l1 > m) { m = l1; mi = lane + 64; }
        if (v2 && l2 > m) { m = l2; mi = lane + 128; }
        // wave reduce: max with lowest-index tiebreak (matches np.argmax)
#pragma unroll
        for (int off = 32; off >= 1; off >>= 1) {
            const float om = __shfl_xor(m, off);
            const int   oi = __shfl_xor(mi, off);
            if (om > m || (om == m && oi < mi)) { m = om; mi = oi; }
        }
        const int tgt = tseq[(size_t)b * TLEN + t];
        float se = expf(l0 - m) + expf(l1 - m) + (v2 ? expf(l2 - m) : 0.f);
        const int ts = tgt >> 6, tl_lane = tgt & 63;
        float tl = (lane == tl_lane) ? ((ts == 0) ? l0 : (ts == 1) ? l1 : l2) : 0.f;
#pragma unroll
        for (int off = 32; off >= 1; off >>= 1) {
            se += __shfl_xor(se, off);
            tl += __shfl_xor(tl, off);
        }
        if (lane == 0) {
            if (mi < OUTC) pred[(size_t)b * OUTC + mi] = 1.0f;
            if (tgt != IGN_TOK) { wnll += (m + logf(se)) - tl; wcnt += 1.f; }
        }
    }
    if (lane == 0) {
        atomicAdd(&accb[0], wnll);
        atomicAdd(&accb[1], wcnt);
    }
}

__global__ void finalize_loss(const float* __restrict__ accb, float* __restrict__ out)
{
    out[0] = accb[0] / fmaxf(accb[1], 1.f);
}

extern "C" void kernel_launch(void* const* d_in, const int* in_sizes, int n_in,
                              void* d_out, int out_size, void* d_ws, size_t ws_size,
                              hipStream_t stream)
{
    const float* s    = (const float*)d_in[0];
    const int*   aseq = (const int*)  d_in[1];
    const float* W1   = (const float*)d_in[2];
    const float* b1   = (const float*)d_in[3];
    const float* W2   = (const float*)d_in[4];
    const float* b2   = (const float*)d_in[5];
    const float* emb  = (const float*)d_in[6];
    const float* Wih  = (const float*)d_in[7];
    const float* Whh  = (const float*)d_in[8];
    const float* bih  = (const float*)d_in[9];
    const float* bhh  = (const float*)d_in[10];
    const float* Wp   = (const float*)d_in[11];
    const float* bp   = (const float*)d_in[12];

    float* ws = (float*)d_ws;
    const size_t off_gh    = 0;                               // 8192*3072 (encoder h1 aliases here)
    const size_t off_gx0   = (size_t)BATCH * G3;              // 8192*3072
    const size_t off_h     = off_gx0 + (size_t)BATCH * G3;    // 8192*1024 (h0, updated in place)
    const size_t off_tokgi = off_h + (size_t)BATCH * DECD;    // 169*3072
    const size_t off_acc   = off_tokgi + (size_t)VOCAB * G3 + 64;
    const size_t need = (off_acc + 64) * sizeof(float);
    if (ws_size < need) return;

    float* gh   = ws + off_gh;
    float* h1   = ws + off_gh;   // encoder temp, consumed before gh is first written
    float* gx0  = ws + off_gx0;
    float* hbuf = ws + off_h;
    float* tg   = ws + off_tokgi;
    float* accb = ws + off_acc;
    float* outp = (float*)d_out;

    hipMemsetAsync(d_out, 0, (size_t)out_size * sizeof(float), stream);
    hipMemsetAsync(accb, 0, 2 * sizeof(float), stream);

    // encoder: h1 = relu(s@W1+b1); h0 = h1@W2+b2
    gemm_f32<<<dim3(HDIM/BN, BATCH/BM), 256, 0, stream>>>(s,  W1, b1, h1,   BATCH, HDIM, SDIM, 1);
    gemm_f32<<<dim3(DECD/BN, BATCH/BM), 256, 0, stream>>>(h1, W2, b2, hbuf, BATCH, DECD, HDIM, 0);
    // gx0 = h0 @ Wih[256:,:] + bih   (constant across steps)
    gemm_f32<<<dim3(G3/BN, BATCH/BM), 256, 0, stream>>>(hbuf, Wih + (size_t)EMBD * G3, bih, gx0,
                                                        BATCH, G3, DECD, 0);
    // tokgi = emb @ Wih[:256,:]
    tok_gi<<<dim3(G3/256, VOCAB), 256, 0, stream>>>(emb, Wih, tg);

    for (int t = 0; t < TLEN; ++t) {
        gemm_f32<<<dim3(G3/BN, BATCH/BM), 256, 0, stream>>>(hbuf, Whh, bhh, gh, BATCH, G3, DECD, 0);
        gru_gates<<<(BATCH * DECD) / 256, 256, 0, stream>>>(gh, gx0, tg, aseq, t, hbuf);
        logits_kernel<<<BATCH / LROWS, 256, 0, stream>>>(hbuf, Wp, bp, aseq, t, outp + 1, accb);
    }
    finalize_loss<<<1, 1, 0, stream>>>(accb, outp);
}